// Round 15
// baseline (383.607 us; speedup 1.0000x reference)
//
#include <hip/hip_runtime.h>

#define Tn 2048
#define Dn 2048
#define Hn 32
#define Cn 32
#define NCH (Tn / Cn)

typedef float f32x4 __attribute__((ext_vector_type(4)));
typedef __bf16 bf16x8 __attribute__((ext_vector_type(8)));
typedef __bf16 bf16x4 __attribute__((ext_vector_type(4)));

// ---- fast wave-64 sum: DPP row reductions (VALU) + readlane ----
template <int CTRL>
__device__ __forceinline__ float dpp_add(float x) {
  int xi = __builtin_bit_cast(int, x);
  int sh = __builtin_amdgcn_update_dpp(0, xi, CTRL, 0xf, 0xf, true);
  return x + __builtin_bit_cast(float, sh);
}
__device__ __forceinline__ float rdlane(float x, int l) {
  int xi = __builtin_bit_cast(int, x);
  return __builtin_bit_cast(float, __builtin_amdgcn_readlane(xi, l));
}
__device__ __forceinline__ float waveSum(float v) {
  v = dpp_add<0x111>(v);
  v = dpp_add<0x112>(v);
  v = dpp_add<0x114>(v);
  v = dpp_add<0x118>(v);
  return (rdlane(v, 15) + rdlane(v, 31)) + (rdlane(v, 47) + rdlane(v, 63));
}

__device__ __forceinline__ float sigm(float x) { return 1.f / (1.f + expf(-x)); }

__device__ __forceinline__ void gl_lds16(const void* g, void* l) {
  __builtin_amdgcn_global_load_lds(
      (__attribute__((address_space(1))) void*)(g),
      (__attribute__((address_space(3))) void*)(l), 16, 0, 0);
}

// barrier that drains only LDS (lgkmcnt), leaving global loads in flight
__device__ __forceinline__ void bar_lgkm() {
  asm volatile("s_waitcnt lgkmcnt(0)" ::: "memory");
  __builtin_amdgcn_s_barrier();
}

__device__ __forceinline__ f32x4 mfma16(const __bf16* a, const __bf16* b, f32x4 acc) {
  return __builtin_amdgcn_mfma_f32_16x16x32_bf16(
      *(const bf16x8*)a, *(const bf16x8*)b, acc, 0, 0, 0);
}

// ---------------- weight casts ----------------

__global__ __launch_bounds__(256) void castw3_kernel(
    const float* __restrict__ A, const float* __restrict__ B,
    const float* __restrict__ C, __bf16* __restrict__ o0,
    __bf16* __restrict__ o1, __bf16* __restrict__ o2) {
  const int z = blockIdx.y;
  const float* src = z == 0 ? A : (z == 1 ? B : C);
  __bf16* dst = z == 0 ? o0 : (z == 1 ? o1 : o2);
  const size_t i4 = (size_t)blockIdx.x * 256 + threadIdx.x;
  f32x4 v = *(const f32x4*)(src + i4 * 4);
  bf16x4 o;
  o[0] = (__bf16)v[0]; o[1] = (__bf16)v[1]; o[2] = (__bf16)v[2]; o[3] = (__bf16)v[3];
  ((bf16x4*)dst)[i4] = o;
}

__global__ __launch_bounds__(256) void cast1_kernel(
    const float* __restrict__ src, __bf16* __restrict__ dst) {
  const size_t i4 = (size_t)blockIdx.x * 256 + threadIdx.x;
  f32x4 v = *(const f32x4*)(src + i4 * 4);
  bf16x4 o;
  o[0] = (__bf16)v[0]; o[1] = (__bf16)v[1]; o[2] = (__bf16)v[2]; o[3] = (__bf16)v[3];
  ((bf16x4*)dst)[i4] = o;
}

// y==0: stage-2 weights -> [D][128] padded; y=1..4: stage-1 -> [128][D] padded
__global__ __launch_bounds__(256) void castTU_kernel(
    const float* __restrict__ w2, const float* __restrict__ a2,
    const float* __restrict__ v2, const float* __restrict__ g2,
    __bf16* __restrict__ w2T, __bf16* __restrict__ a2T,
    __bf16* __restrict__ v2T, __bf16* __restrict__ g2T,
    const float* __restrict__ w1, const float* __restrict__ a1,
    const float* __restrict__ v1, const float* __restrict__ g1,
    __bf16* __restrict__ uwT, __bf16* __restrict__ uaT,
    __bf16* __restrict__ uvT, __bf16* __restrict__ ugT) {
  const int k = threadIdx.x;
  if (k >= 128) return;
  const int y = blockIdx.y;
  if (y == 0) {
    const int i = blockIdx.x;
    w2T[(size_t)i * 128 + k] = (k < 64) ? (__bf16)w2[(size_t)k * Dn + i] : (__bf16)0.f;
    a2T[(size_t)i * 128 + k] = (k < 64) ? (__bf16)a2[(size_t)k * Dn + i] : (__bf16)0.f;
    v2T[(size_t)i * 128 + k] = (k < 32) ? (__bf16)v2[(size_t)k * Dn + i] : (__bf16)0.f;
    g2T[(size_t)i * 128 + k] = (__bf16)g2[(size_t)k * Dn + i];
  } else {
    const int z = y - 1;
    const float* src = z == 0 ? w1 : (z == 1 ? a1 : (z == 2 ? v1 : g1));
    __bf16* dst = z == 0 ? uwT : (z == 1 ? uaT : (z == 2 ? uvT : ugT));
    const int R = z == 0 ? 64 : (z == 1 ? 64 : (z == 2 ? 32 : 128));
    const int d = blockIdx.x;
    dst[(size_t)k * Dn + d] = (k < R) ? (__bf16)src[(size_t)d * R + k] : (__bf16)0.f;
  }
}

// ---------------- fused ln1 + token-shift mix ----------------

__global__ __launch_bounds__(256) void lnmix_kernel(
    const float* __restrict__ x, const float* __restrict__ state1,
    const float* __restrict__ lw, const float* __restrict__ lb,
    const float* __restrict__ cr, const float* __restrict__ cw,
    const float* __restrict__ ck, const float* __restrict__ cv,
    const float* __restrict__ ca, const float* __restrict__ cg,
    __bf16* __restrict__ br, __bf16* __restrict__ bw, __bf16* __restrict__ bk,
    __bf16* __restrict__ bv, __bf16* __restrict__ ba, __bf16* __restrict__ bg,
    float* __restrict__ xn_last) {
  __shared__ float red[16];
  const int t = blockIdx.x, tid = threadIdx.x;
  const int lane = tid & 63, wv = tid >> 6;
  const float* xc = x + (size_t)t * Dn;
  const float* xp = x + (size_t)(t - 1) * Dn;
  float vc[8], vp[8];
  float sc = 0.f, sp = 0.f;
#pragma unroll
  for (int c = 0; c < 8; ++c) {
    vc[c] = xc[tid + c * 256]; sc += vc[c];
    vp[c] = (t > 0) ? xp[tid + c * 256] : 0.f; sp += vp[c];
  }
  sc = waveSum(sc); sp = waveSum(sp);
  if (lane == 0) { red[wv] = sc; red[8 + wv] = sp; }
  __syncthreads();
  const float mu_c = (red[0] + red[1] + red[2] + red[3]) * (1.f / (float)Dn);
  const float mu_p = (red[8] + red[9] + red[10] + red[11]) * (1.f / (float)Dn);
  float qc = 0.f, qp = 0.f;
#pragma unroll
  for (int c = 0; c < 8; ++c) {
    float d0 = vc[c] - mu_c; qc += d0 * d0;
    float d1 = vp[c] - mu_p; qp += d1 * d1;
  }
  qc = waveSum(qc); qp = waveSum(qp);
  if (lane == 0) { red[4 + wv] = qc; red[12 + wv] = qp; }
  __syncthreads();
  const float var_c = (red[4] + red[5] + red[6] + red[7]) * (1.f / (float)Dn);
  const float var_p = (red[12] + red[13] + red[14] + red[15]) * (1.f / (float)Dn);
  const float rstd_c = rsqrtf(var_c + 1e-5f);
  const float rstd_p = rsqrtf(var_p + 1e-5f);
#pragma unroll
  for (int c = 0; c < 8; ++c) {
    const int d = tid + c * 256;
    const size_t idx = (size_t)t * Dn + d;
    const float lwd = lw[d], lbd = lb[d];
    const float ync = (vc[c] - mu_c) * rstd_c * lwd + lbd;
    const float ynp = (t > 0) ? ((vp[c] - mu_p) * rstd_p * lwd + lbd) : state1[d];
    const float sx = ynp - ync;
    br[idx] = (__bf16)(ync + sx * cr[d]);
    bw[idx] = (__bf16)(ync + sx * cw[d]);
    bk[idx] = (__bf16)(ync + sx * ck[d]);
    bv[idx] = (__bf16)(ync + sx * cv[d]);
    ba[idx] = (__bf16)(ync + sx * ca[d]);
    bg[idx] = (__bf16)(ync + sx * cg[d]);
    if (t == Tn - 1) xn_last[d] = ync;
  }
}

// ---------------- MFMA GEMM tile core: 2-phase double-buffered ----------------
// STAGE(next) issued BEFORE compute(cur); single barrier per K-step whose
// vmcnt drain lands after a full compute phase of overlap (guide T3 minimum).

__device__ __forceinline__ void gemm_tile(const __bf16* __restrict__ A,
                                          const __bf16* __restrict__ B,
                                          int K, int row0, int col0,
                                          f32x4 (&acc)[4][4]) {
  __shared__ __attribute__((aligned(16))) __bf16 As[2][4096];
  __shared__ __attribute__((aligned(16))) __bf16 Bs[2][4096];
  const int tid = threadIdx.x;
  const int lane = tid & 63, wid = tid >> 6;
  const int wm = (wid >> 1) * 64, wn = (wid & 1) * 64;
  const int lr = lane & 15, lk = (lane >> 4) * 8;
  auto stage = [&](int buf, int kt) {
#pragma unroll
    for (int it = 0; it < 2; ++it) {
      const int L = it * 256 + tid;
      const int rr = L >> 2, kc = (L & 3) * 8;
      const int lb = (it * 256 + wid * 64) * 8;
      gl_lds16(A + (size_t)(row0 + rr) * K + (kt + kc), &As[buf][lb]);
      gl_lds16(B + (size_t)(col0 + rr) * K + (kt + kc), &Bs[buf][lb]);
    }
  };
  stage(0, 0);
  __syncthreads();
  int cur = 0;
  for (int kt = 0; kt < K; kt += 32) {
    if (kt + 32 < K) stage(cur ^ 1, kt + 32);   // prefetch next tile
    bf16x8 af[4], bfv[4];
#pragma unroll
    for (int mf = 0; mf < 4; ++mf)
      af[mf] = *(const bf16x8*)&As[cur][(wm + mf * 16 + lr) * 32 + lk];
#pragma unroll
    for (int nf = 0; nf < 4; ++nf)
      bfv[nf] = *(const bf16x8*)&Bs[cur][(wn + nf * 16 + lr) * 32 + lk];
#pragma unroll
    for (int mf = 0; mf < 4; ++mf)
#pragma unroll
      for (int nf = 0; nf < 4; ++nf)
        acc[mf][nf] = __builtin_amdgcn_mfma_f32_16x16x32_bf16(
            af[mf], bfv[nf], acc[mf][nf], 0, 0, 0);
    __syncthreads();   // drains vmcnt (next buf ready) + reads of cur done
    cur ^= 1;
  }
}

// XCD region swizzle for 16x16 grids: each XCD owns a 4x8 tile region
__device__ __forceinline__ void xcd_swz16(int& bx, int& by) {
  const int lid = bx + (by << 4);
  const int xcd = lid & 7, idx = lid >> 3;
  bx = ((xcd & 3) << 2) + (idx & 3);
  by = ((xcd >> 2) << 3) + (idx >> 2);
}

// r/k/v (z=0..2, full y-grid, swizzled) + LoRA stage-1 (z=3..6, y==0 only)
__global__ __launch_bounds__(256) void gemm37_kernel(
    const __bf16* __restrict__ A0, const __bf16* __restrict__ A1,
    const __bf16* __restrict__ A2, const __bf16* __restrict__ B0,
    const __bf16* __restrict__ B1, const __bf16* __restrict__ B2,
    __bf16* __restrict__ C0, __bf16* __restrict__ C1, __bf16* __restrict__ C2,
    const __bf16* __restrict__ Aw, const __bf16* __restrict__ Aa,
    const __bf16* __restrict__ Av, const __bf16* __restrict__ Ag,
    const __bf16* __restrict__ Bw, const __bf16* __restrict__ Ba,
    const __bf16* __restrict__ Bv, const __bf16* __restrict__ Bg,
    __bf16* __restrict__ Cw, __bf16* __restrict__ Ca,
    __bf16* __restrict__ Cv, __bf16* __restrict__ Cg) {
  const int z = blockIdx.z;
  if (z >= 3 && blockIdx.y != 0) return;
  const __bf16* A; const __bf16* B; __bf16* C;
  switch (z) {
    case 0: A = A0; B = B0; C = C0; break;
    case 1: A = A1; B = B1; C = C1; break;
    case 2: A = A2; B = B2; C = C2; break;
    case 3: A = Aw; B = Bw; C = Cw; break;
    case 4: A = Aa; B = Ba; C = Ca; break;
    case 5: A = Av; B = Bv; C = Cv; break;
    default: A = Ag; B = Bg; C = Cg; break;
  }
  int bx = blockIdx.x, by = blockIdx.y;
  if (z < 3) xcd_swz16(bx, by);
  const int row0 = bx * 128, col0 = (z < 3) ? by * 128 : 0;
  const int ldc = (z < 3) ? Dn : 128;
  f32x4 acc[4][4] = {};
  gemm_tile(A, B, Dn, row0, col0, acc);
  const int lane = threadIdx.x & 63, wid = threadIdx.x >> 6;
  const int wm = (wid >> 1) * 64, wn = (wid & 1) * 64;
#pragma unroll
  for (int mf = 0; mf < 4; ++mf) {
    const int r0 = row0 + wm + mf * 16 + ((lane >> 4) << 2);
#pragma unroll
    for (int nf = 0; nf < 4; ++nf) {
      const int c0 = col0 + wn + nf * 16 + (lane & 15);
#pragma unroll
      for (int rg = 0; rg < 4; ++rg) {
        float val = acc[mf][nf][rg];
        if (z == 3)      val = tanhf(val);
        else if (z == 6) val = sigm(val);
        C[(size_t)(r0 + rg) * ldc + c0] = (__bf16)val;
      }
    }
  }
}

// LoRA stage-2 fused, uniform K=128 (zero-padded)
__global__ __launch_bounds__(256) void gemm_s2_kernel(
    const __bf16* __restrict__ Aw, const __bf16* __restrict__ Aa,
    const __bf16* __restrict__ Av, const __bf16* __restrict__ Ag,
    const __bf16* __restrict__ Bw, const __bf16* __restrict__ Ba,
    const __bf16* __restrict__ Bv, const __bf16* __restrict__ Bg,
    const float* __restrict__ w0, const float* __restrict__ a0,
    const float* __restrict__ v0, __bf16* __restrict__ Cw,
    __bf16* __restrict__ Ca, __bf16* __restrict__ Cv, __bf16* __restrict__ Cg) {
  const int z = blockIdx.z;
  const __bf16* A = z == 0 ? Aw : (z == 1 ? Aa : (z == 2 ? Av : Ag));
  const __bf16* B = z == 0 ? Bw : (z == 1 ? Ba : (z == 2 ? Bv : Bg));
  const float* bias = z == 0 ? w0 : (z == 1 ? a0 : (z == 2 ? v0 : (const float*)0));
  __bf16* C = z == 0 ? Cw : (z == 1 ? Ca : (z == 2 ? Cv : Cg));
  const int row0 = blockIdx.x * 128, col0 = blockIdx.y * 128;
  f32x4 acc[4][4] = {};
  gemm_tile(A, B, 128, row0, col0, acc);
  const int lane = threadIdx.x & 63, wid = threadIdx.x >> 6;
  const int wm = (wid >> 1) * 64, wn = (wid & 1) * 64;
#pragma unroll
  for (int mf = 0; mf < 4; ++mf) {
    const int r0 = row0 + wm + mf * 16 + ((lane >> 4) << 2);
#pragma unroll
    for (int nf = 0; nf < 4; ++nf) {
      const int c0 = col0 + wn + nf * 16 + (lane & 15);
#pragma unroll
      for (int rg = 0; rg < 4; ++rg) {
        float val = acc[mf][nf][rg];
        if (z == 0)      val = expf(-0.606531f * sigm(val + bias[c0]));
        else if (z < 3)  val = sigm(val + bias[c0]);
        C[(size_t)(r0 + rg) * Dn + c0] = (__bf16)val;
      }
    }
  }
}

__global__ __launch_bounds__(256) void gemm_wo_kernel(
    const __bf16* __restrict__ A, const __bf16* __restrict__ B,
    const float* __restrict__ xres, float* __restrict__ C) {
  int bx = blockIdx.x, by = blockIdx.y;
  xcd_swz16(bx, by);
  const int row0 = bx * 128, col0 = by * 128;
  f32x4 acc[4][4] = {};
  gemm_tile(A, B, Dn, row0, col0, acc);
  const int lane = threadIdx.x & 63, wid = threadIdx.x >> 6;
  const int wm = (wid >> 1) * 64, wn = (wid & 1) * 64;
#pragma unroll
  for (int mf = 0; mf < 4; ++mf) {
    const int r0 = row0 + wm + mf * 16 + ((lane >> 4) << 2);
#pragma unroll
    for (int nf = 0; nf < 4; ++nf) {
      const int c0 = col0 + wn + nf * 16 + (lane & 15);
#pragma unroll
      for (int rg = 0; rg < 4; ++rg)
        C[(size_t)(r0 + rg) * Dn + c0] =
            acc[mf][nf][rg] + xres[(size_t)(r0 + rg) * Dn + c0];
    }
  }
}

// ---------------- prep ----------------

__global__ __launch_bounds__(256) void prep_kernel(
    const __bf16* __restrict__ r, __bf16* __restrict__ k, __bf16* __restrict__ v,
    const __bf16* __restrict__ a, const __bf16* __restrict__ vb,
    const float* __restrict__ v_first, const float* __restrict__ k_k,
    const float* __restrict__ k_a, const float* __restrict__ r_k,
    __bf16* __restrict__ kk_out, __bf16* __restrict__ ab_out,
    float* __restrict__ dot_out) {
  const int t = blockIdx.x;
  const int lane = threadIdx.x & 63, wv = threadIdx.x >> 6;
#pragma unroll 1
  for (int c = 0; c < 8; ++c) {
    const int d = c * 256 + wv * 64 + lane;
    const size_t idx = (size_t)t * Dn + d;
    const float kvv = (float)k[idx];
    const float kh = kvv * k_k[d];
    const float nrm = sqrtf(waveSum(kh * kh)) + 1e-6f;
    const float kkv = kh / nrm;
    const float av = (float)a[idx];
    float vv = (float)v[idx];
    vv = vv + (v_first[idx] - vv) * (float)vb[idx];
    const float kfv = kvv * (1.f + (av - 1.f) * k_a[d]);
    const float dt = waveSum((float)r[idx] * kfv * r_k[d]);
    kk_out[idx] = (__bf16)kkv;
    ab_out[idx] = (__bf16)(kkv * av);
    k[idx] = (__bf16)kfv;
    v[idx] = (__bf16)vv;
    if (lane == 0) dot_out[t * Hn + (d >> 6)] = dt;
  }
}

// ---------------- chunkA: all matrix products on MFMA ----------------

__global__ __launch_bounds__(256) void chunkA_kernel(
    const __bf16* __restrict__ wd, const __bf16* __restrict__ kk,
    const __bf16* __restrict__ ab, const __bf16* __restrict__ kf,
    const __bf16* __restrict__ r,
    __bf16* __restrict__ PAg, __bf16* __restrict__ Rtil,
    __bf16* __restrict__ BhatT, __bf16* __restrict__ KhatT,
    __bf16* __restrict__ PKg,
    __bf16* __restrict__ Gbg, __bf16* __restrict__ Gkg,
    float* __restrict__ WCg) {
  const int c = blockIdx.x, h = blockIdx.y;
  const int tid = threadIdx.x;
  const int lane = tid & 63, wid = tid >> 6;
  const int lr = lane & 15, lg = lane >> 4, lk = lg * 8;
  __shared__ __attribute__((aligned(16))) __bf16 A_l[32][72];
  __shared__ __attribute__((aligned(16))) __bf16 B_l[32][72], K_l[32][72], R_l[32][72];
  __shared__ __attribute__((aligned(16))) __bf16 At_t[64][40];
  __shared__ float W_l[33][64];
  __shared__ __attribute__((aligned(16))) __bf16 Mn[32][40], Mt[32][40], Mkat[32][40];
  __shared__ __attribute__((aligned(16))) __bf16 Pa[32][40], Pb[32][40];
  __shared__ __attribute__((aligned(16))) __bf16 Tn_[32][40], Tt_[32][40];
  __shared__ __attribute__((aligned(16))) __bf16 Un_[32][40], Ut_[32][40];

  const size_t rowbase = (size_t)(c * Cn) * Dn + (size_t)h * 64;
  const int tt = tid >> 3, j0 = (tid & 7) * 8;
  const size_t g = rowbase + (size_t)tt * Dn + j0;
  *(bf16x8*)&A_l[tt][j0] = *(const bf16x8*)(wd + g);
  __syncthreads();
  if (tid < 64) {
    const int j = tid;
    float cur = 1.f;
    W_l[0][j] = 1.f;
    for (int t = 0; t < Cn; ++t) {
      cur *= (float)A_l[t][j];
      W_l[t + 1][j] = cur;
    }
    WCg[((size_t)c * Hn + h) * 64 + j] = cur;
  }
  __syncthreads();
  {
    bf16x8 kkv = *(const bf16x8*)(kk + g);
    bf16x8 abv = *(const bf16x8*)(ab + g);
    bf16x8 kv  = *(const bf16x8*)(kf + g);
    bf16x8 rv  = *(const bf16x8*)(r + g);
    bf16x8 oa, ob, ok, orr;
    const size_t tb = ((size_t)c * Hn + h) * 2048;
#pragma unroll
    for (int e = 0; e < 8; ++e) {
      const int j = j0 + e;
      const float Wexc = W_l[tt][j], Winc = W_l[tt + 1][j], WC = W_l[32][j];
      const float inv = 1.f / Winc;
      const float at = -(float)kkv[e] * Wexc;
      const float bt = (float)abv[e] * inv;
      const float kt = (float)kv[e] * inv;
      const float rt = (float)rv[e] * Winc;
      oa[e] = (__bf16)at; ob[e] = (__bf16)bt; ok[e] = (__bf16)kt;
      orr[e] = (__bf16)rt;
      At_t[j][tt] = (__bf16)at;
      BhatT[tb + (size_t)j * 32 + tt] = (__bf16)(bt * WC);
      KhatT[tb + (size_t)j * 32 + tt] = (__bf16)(kt * WC);
    }
    *(bf16x8*)&A_l[tt][j0] = oa;
    *(bf16x8*)&B_l[tt][j0] = ob;
    *(bf16x8*)&K_l[tt][j0] = ok;
    *(bf16x8*)&R_l[tt][j0] = orr;
    *(bf16x8*)(Rtil + g) = orr;
  }
  __syncthreads();
  const size_t matbase = ((size_t)c * Hn + h) * (Cn * Cn);
  {
    const __bf16 (*Ax)[72] = (wid < 2) ? A_l : R_l;
    const __bf16 (*Bx)[72] = ((wid & 1) == 0) ? B_l : K_l;
#pragma unroll
    for (int tile = 0; tile < 4; ++tile) {
      const int tm = (tile >> 1) * 16, tn = (tile & 1) * 16;
      f32x4 acc = {};
      acc = mfma16(&Ax[tm + lr][lk], &Bx[tn + lr][lk], acc);
      acc = mfma16(&Ax[tm + lr][32 + lk], &Bx[tn + lr][32 + lk], acc);
      const int col = tn + lr;
#pragma unroll
      for (int e = 0; e < 4; ++e) {
        const int row = tm + lg * 4 + e;
        if (wid == 0) {
          const __bf16 v = (__bf16)((col < row) ? acc[e] : 0.f);
          Mn[row][col] = v; Mt[col][row] = v;
        } else if (wid == 1) {
          Mkat[col][row] = (__bf16)((col < row) ? acc[e] : 0.f);
        } else if (wid == 2) {
          Gbg[matbase + row * 32 + col] = (__bf16)((col <= row) ? acc[e] : 0.f);
        } else {
          Gkg[matbase + row * 32 + col] = (__bf16)((col <= row) ? acc[e] : 0.f);
        }
      }
    }
  }
  __syncthreads();
  for (int rep = 0; rep < 4; ++rep) {
    const int id = rep * 256 + tid;
    const int t = id >> 5, ta = id & 31;
    Pa[t][ta] = (__bf16)((float)Mn[t][ta] + (t == ta ? 1.f : 0.f));
  }
  __syncthreads();
  const int tm = (wid >> 1) * 16, tn = (wid & 1) * 16;
  auto sq = [&](__bf16 (*Dn_)[40], __bf16 (*Dt_)[40],
                __bf16 (*Xn)[40], __bf16 (*Xt)[40]) {
    f32x4 acc = {};
    acc = mfma16(&Xn[tm + lr][lk], &Xt[tn + lr][lk], acc);
    const int col = tn + lr;
#pragma unroll
    for (int e = 0; e < 4; ++e) {
      const int row = tm + lg * 4 + e;
      const __bf16 v = (__bf16)acc[e];
      Dn_[row][col] = v; Dt_[col][row] = v;
    }
    __syncthreads();
  };
  auto pup = [&](__bf16 (*Dn_)[40], __bf16 (*Pn)[40], __bf16 (*Tt)[40]) {
    f32x4 acc;
    const int col = tn + lr;
#pragma unroll
    for (int e = 0; e < 4; ++e) acc[e] = (float)Pn[tm + lg * 4 + e][col];
    acc = mfma16(&Pn[tm + lr][lk], &Tt[tn + lr][lk], acc);
#pragma unroll
    for (int e = 0; e < 4; ++e) Dn_[tm + lg * 4 + e][col] = (__bf16)acc[e];
    __syncthreads();
  };
  sq(Tn_, Tt_, Mn, Mt);
  pup(Pb, Pa, Tt_);
  sq(Un_, Ut_, Tn_, Tt_);
  pup(Pa, Pb, Ut_);
  sq(Tn_, Tt_, Un_, Ut_);
  pup(Pb, Pa, Tt_);
  sq(Un_, Ut_, Tn_, Tt_);
  pup(Pa, Pb, Ut_);
  {
    f32x4 acc = {};
    acc = mfma16(&Pa[tm + lr][lk], &Mkat[tn + lr][lk], acc);
    const int col = tn + lr;
#pragma unroll
    for (int e = 0; e < 4; ++e)
      PKg[matbase + (tm + lg * 4 + e) * 32 + col] = (__bf16)acc[e];
  }
#pragma unroll
  for (int half = 0; half < 2; ++half) {
    const int jn = (wid & 1) * 16 + half * 32;
    f32x4 acc = {};
    acc = mfma16(&Pa[tm + lr][lk], &At_t[jn + lr][lk], acc);
    const int col = jn + lr;
#pragma unroll
    for (int e = 0; e < 4; ++e)
      PAg[rowbase + (size_t)(tm + lg * 4 + e) * Dn + col] = (__bf16)acc[e];
  }
}

// ---------------- vt: vbuf [t][D] -> Vt [c][h][i][t] ----------------

__global__ __launch_bounds__(256) void vt_kernel(
    const __bf16* __restrict__ vbuf, __bf16* __restrict__ Vt) {
  const int c = blockIdx.x, h = blockIdx.y;
  __shared__ __bf16 tile[32][72];
  const int tid = threadIdx.x;
  {
    const int t = tid >> 3, i0 = (tid & 7) * 8;
    *(bf16x8*)&tile[t][i0] =
        *(const bf16x8*)(vbuf + (size_t)(c * Cn + t) * Dn + h * 64 + i0);
  }
  __syncthreads();
  {
    const int i = tid >> 2, t0 = (tid & 3) * 8;
    bf16x8 o;
#pragma unroll
    for (int e = 0; e < 8; ++e) o[e] = tile[t0 + e][i];
    *(bf16x8*)(Vt + ((size_t)c * Hn + h) * 2048 + (size_t)i * 32 + t0) = o;
  }
}

// ---------------- chunkB: MFMA, 2 compute phases (PA-fused), 64 blocks ----------------

__global__ __launch_bounds__(256) void chunkB_kernel(
    const __bf16* __restrict__ PAg, const __bf16* __restrict__ Rtil,
    const __bf16* __restrict__ BhatT, const __bf16* __restrict__ KhatT,
    const __bf16* __restrict__ PKg,
    const __bf16* __restrict__ Gbg, const __bf16* __restrict__ Gkg,
    const float* __restrict__ WCg, const __bf16* __restrict__ Vt,
    const float* __restrict__ st_in, __bf16* __restrict__ xo,
    float* __restrict__ st_out) {
  const int b = blockIdx.x;
  const int xcd = b & 7, rest = b >> 3;
  const int h = xcd * 4 + (rest & 3);
  const int io = (rest >> 2) * 32;
  const int tid = threadIdx.x;
  const int lane = tid & 63, wid = tid >> 6;
  const int lr = lane & 15, lg = lane >> 4;
  const int lk = lg * 8;

  __shared__ __attribute__((aligned(16))) float S_l[32][68];
  __shared__ __attribute__((aligned(16))) __bf16 Sb_l[32][72];
  __shared__ __attribute__((aligned(16))) __bf16 PA_l[32][72], R_l[32][72];
  __shared__ __attribute__((aligned(16))) __bf16 BhT_l[64][40], KhT_l[64][40];
  __shared__ __attribute__((aligned(16))) __bf16 Vt_l[32][40];
  __shared__ __attribute__((aligned(16))) __bf16 PK_l[32][40];
  __shared__ __attribute__((aligned(16))) __bf16 Gb_l[32][40], Gk_l[32][40];
  __shared__ __attribute__((aligned(16))) __bf16 SA_l[32][40];
  __shared__ float WC_l[64];

  {
    const int i = tid >> 3, j0 = (tid & 7) * 8;
    const float* src = st_in + (size_t)h * 4096 + (size_t)(io + i) * 64 + j0;
    *(f32x4*)&S_l[i][j0] = *(const f32x4*)src;
    *(f32x4*)&S_l[i][j0 + 4] = *(const f32x4*)(src + 4);
  }

  bf16x8 rPA, rR, rBh, rKh;
  bf16x4 rV, rPK, rGb, rGk;
  float rWC = 0.f;

  auto load_regs = [&](int c) {
    const size_t rb = (size_t)(c * Cn) * Dn + (size_t)h * 64;
    {
      const int t = tid >> 3, j0 = (tid & 7) * 8;
      rPA = *(const bf16x8*)(PAg + rb + (size_t)t * Dn + j0);
      rR  = *(const bf16x8*)(Rtil + rb + (size_t)t * Dn + j0);
    }
    const size_t tb = ((size_t)c * Hn + h) * 2048;
    {
      const int jj = tid >> 2, t0 = (tid & 3) * 8;
      rBh = *(const bf16x8*)(BhatT + tb + (size_t)jj * 32 + t0);
      rKh = *(const bf16x8*)(KhatT + tb + (size_t)jj * 32 + t0);
    }
    {
      const int i = tid >> 3, t0 = (tid & 7) * 4;
      rV = *(const bf16x4*)(Vt + tb + (size_t)(io + i) * 32 + t0);
    }
    const size_t mb = ((size_t)c * Hn + h) * 1024 + (size_t)tid * 4;
    rPK = *(const bf16x4*)(PKg + mb);
    rGb = *(const bf16x4*)(Gbg + mb);
    rGk = *(const bf16x4*)(Gkg + mb);
    if (tid < 64) rWC = WCg[((size_t)c * Hn + h) * 64 + tid];
  };
  auto store_lds = [&]() {
    {
      const int t = tid >> 3, j0 = (tid & 7) * 8;
      *(bf16x8*)&PA_l[t][j0] = rPA;
      *(bf16x8*)&R_l[t][j0] = rR;
    }
    {
      const int jj = tid >> 2, t0 = (tid & 3) * 8;
      *(bf16x8*)&BhT_l[jj][t0] = rBh;
      *(bf16x8*)&KhT_l[jj][t0] = rKh;
    }
    {
      const int i = tid >> 3, t0 = (tid & 7) * 4;
      *(bf16x4*)&Vt_l[i][t0] = rV;
    }
    {
      const int t = tid >> 3, u0 = (tid & 7) * 4;
      *(bf16x4*)&PK_l[t][u0] = rPK;
      *(bf16x4*)&Gb_l[t][u0] = rGb;
      *(bf16x4*)&Gk_l[t][u0] = rGk;
    }
    if (tid < 64) WC_l[tid] = rWC;
  };
  auto sb_refresh = [&]() {
    const int i = tid >> 3, j0 = (tid & 7) * 8;
    bf16x8 o;
#pragma unroll
    for (int e = 0; e < 8; ++e) o[e] = (__bf16)S_l[i][j0 + e];
    *(bf16x8*)&Sb_l[i][j0] = o;
  };

  load_regs(0);
  store_lds();
  sb_refresh();
  bar_lgkm();

  const int tm = (wid >> 1) * 16, tn = (wid & 1) * 16;

#pragma unroll 1
  for (int c = 0; c < NCH; ++c) {
    load_regs(c + 1 < NCH ? c + 1 : c);
    // SA = PA*Sb^T + PK*V
    {
      f32x4 acc = {};
      acc = mfma16(&PA_l[tm + lr][lk], &Sb_l[tn + lr][lk], acc);
      acc = mfma16(&PA_l[tm + lr][32 + lk], &Sb_l[tn + lr][32 + lk], acc);
      acc = mfma16(&PK_l[tm + lr][lk], &Vt_l[tn + lr][lk], acc);
      bf16x4 o;
#pragma unroll
      for (int e = 0; e < 4; ++e) o[e] = (__bf16)acc[e];
      *(bf16x4*)&SA_l[tn + lr][tm + lg * 4] = o;
    }
    bar_lgkm();
    // O = Gb*SA + Gk*V + Rtil*Sb^T
    {
      f32x4 acc = {};
      acc = mfma16(&Gb_l[tm + lr][lk], &SA_l[tn + lr][lk], acc);
      acc = mfma16(&Gk_l[tm + lr][lk], &Vt_l[tn + lr][lk], acc);
      acc = mfma16(&R_l[tm + lr][lk], &Sb_l[tn + lr][lk], acc);
      acc = mfma16(&R_l[tm + lr][32 + lk], &Sb_l[tn + lr][32 + lk], acc);
      const int ig = h * 64 + io + tn + lr;
#pragma unroll
      for (int e = 0; e < 4; ++e)
        xo[(size_t)(c * Cn + tm + lg * 4 + e) * Dn + ig] = (__bf16)acc[e];
    }
    // S' = S.*WC + SA^T*Bh + V^T*Kh
#pragma unroll
    for (int tt2 = 0; tt2 < 2; ++tt2) {
      const int tix = wid + tt2 * 4;
      const int im = (tix & 1) * 16, jn = (tix >> 1) * 16;
      const float wc = WC_l[jn + lr];
      f32x4 acc;
#pragma unroll
      for (int e = 0; e < 4; ++e) acc[e] = S_l[im + lg * 4 + e][jn + lr] * wc;
      acc = mfma16(&SA_l[im + lr][lk], &BhT_l[jn + lr][lk], acc);
      acc = mfma16(&Vt_l[im + lr][lk], &KhT_l[jn + lr][lk], acc);
#pragma unroll
      for (int e = 0; e < 4; ++e) S_l[im + lg * 4 + e][jn + lr] = acc[e];
    }
    bar_lgkm();
    store_lds();
    sb_refresh();
    bar_lgkm();
  }
  {
    const int i = tid >> 3, j0 = (tid & 7) * 8;
    float* dst = st_out + (size_t)h * 4096 + (size_t)(io + i) * 64 + j0;
    *(f32x4*)dst = *(const f32x4*)&S_l[i][j0];
    *(f32x4*)(dst + 4) = *(const f32x4*)&S_l[i][j0 + 4];
  }
}

// ---------------- post ----------------

__global__ __launch_bounds__(256) void post_kernel(
    const __bf16* __restrict__ xo, const __bf16* __restrict__ v,
    const __bf16* __restrict__ g, const float* __restrict__ dot,
    const float* __restrict__ lnw, const float* __restrict__ lnb,
    __bf16* __restrict__ out) {
  const int t = blockIdx.x;
  const int lane = threadIdx.x & 63, wv = threadIdx.x >> 6;
#pragma unroll 1
  for (int c = 0; c < 8; ++c) {
    const int d = c * 256 + wv * 64 + lane;
    const size_t idx = (size_t)t * Dn + d;
    const float val = (float)xo[idx];
    const float mu = waveSum(val) * (1.f / 64.f);
    const float ctr = val - mu;
    const float var = waveSum(ctr * ctr) * (1.f / 64.f);
    float y = ctr * rsqrtf(var + 0.00064f);
    y = y * lnw[d] + lnb[d];
    const float res = (y + dot[t * Hn + (d >> 6)] * (float)v[idx]) * (float)g[idx];
    out[idx] = (__bf16)res;
  }
}

// ---------------- launcher ----------------

extern "C" void kernel_launch(void* const* d_in, const int* in_sizes, int n_in,
                              void* d_out, int out_size, void* d_ws, size_t ws_size,
                              hipStream_t stream) {
  (void)in_sizes; (void)n_in; (void)out_size; (void)ws_size;
  const float* x       = (const float*)d_in[0];
  const float* state1  = (const float*)d_in[1];
  const float* state2  = (const float*)d_in[2];
  const float* v_first = (const float*)d_in[3];
  const float* ln1_w   = (const float*)d_in[4];
  const float* ln1_b   = (const float*)d_in[5];
  const float* x_r     = (const float*)d_in[6];
  const float* x_w     = (const float*)d_in[7];
  const float* x_k     = (const float*)d_in[8];
  const float* x_v     = (const float*)d_in[9];
  const float* x_a     = (const float*)d_in[10];
  const float* x_g     = (const float*)d_in[11];
  const float* W_r     = (const float*)d_in[12];
  const float* W_k     = (const float*)d_in[13];
  const float* W_v     = (const float*)d_in[14];
  const float* W_o     = (const float*)d_in[15];
  const float* w1      = (const float*)d_in[16];
  const float* w2      = (const float*)d_in[17];
  const float* w0      = (const float*)d_in[18];
  const float* a1      = (const float*)d_in[19];
  const float* a2      = (const float*)d_in[20];
  const float* a0      = (const float*)d_in[21];
  const float* v1      = (const float*)d_in[22];
  const float* v2      = (const float*)d_in[23];
  const float* v0      = (const float*)d_in[24];
  const float* g1      = (const float*)d_in[25];
  const float* g2      = (const float*)d_in[26];
  const float* k_k     = (const float*)d_in[27];
  const float* k_a     = (const float*)d_in[28];
  const float* r_k     = (const float*)d_in[29];
  const float* lnx_w   = (const float*)d_in[30];
  const float* lnx_b   = (const float*)d_in[31];

  char* p = (char*)d_ws;
  const size_t MB = 1ull << 20;
  __bf16* PAg   = (__bf16*)(p + 0 * MB);
  __bf16* xr_b  = (__bf16*)(p + 8 * MB);
  __bf16* Wo_b  = (__bf16*)(p + 8 * MB);
  __bf16* xw_b  = (__bf16*)(p + 16 * MB);
  __bf16* wdec  = (__bf16*)(p + 16 * MB);
  __bf16* xo_b  = (__bf16*)(p + 16 * MB);
  __bf16* xk_b  = (__bf16*)(p + 24 * MB);
  __bf16* abuf  = (__bf16*)(p + 24 * MB);
  __bf16* Rtil  = (__bf16*)(p + 24 * MB);
  __bf16* xv_b  = (__bf16*)(p + 32 * MB);
  __bf16* vbl   = (__bf16*)(p + 32 * MB);
  __bf16* BhatT = (__bf16*)(p + 32 * MB);
  __bf16* xa_b  = (__bf16*)(p + 40 * MB);
  __bf16* gbuf  = (__bf16*)(p + 40 * MB);
  __bf16* xg_b  = (__bf16*)(p + 48 * MB);
  __bf16* kkbuf = (__bf16*)(p + 48 * MB);
  __bf16* xobuf = (__bf16*)(p + 48 * MB);
  __bf16* Wr_b  = (__bf16*)(p + 56 * MB);
  __bf16* abbuf = (__bf16*)(p + 56 * MB);
  __bf16* Wk_b  = (__bf16*)(p + 64 * MB);
  __bf16* KhatT = (__bf16*)(p + 64 * MB);
  __bf16* Wv_b  = (__bf16*)(p + 72 * MB);
  __bf16* PKg   = (__bf16*)(p + 72 * MB);
  __bf16* rbuf  = (__bf16*)(p + 80 * MB);
  __bf16* kbuf  = (__bf16*)(p + 88 * MB);
  __bf16* Vt    = (__bf16*)(p + 88 * MB);   // kbuf dead after chunkA
  __bf16* vbuf  = (__bf16*)(p + 96 * MB);
  __bf16* Gbg   = (__bf16*)(p + 104 * MB);
  __bf16* Gkg   = (__bf16*)(p + 108 * MB);
  char* q = p + 112 * MB;
  __bf16* yw  = (__bf16*)q; q += (size_t)Tn * 128 * 2;
  __bf16* ya  = (__bf16*)q; q += (size_t)Tn * 128 * 2;
  __bf16* yv  = (__bf16*)q; q += (size_t)Tn * 128 * 2;
  __bf16* yg  = (__bf16*)q; q += (size_t)Tn * 128 * 2;
  __bf16* uwT = (__bf16*)q; q += (size_t)128 * Dn * 2;
  __bf16* uaT = (__bf16*)q; q += (size_t)128 * Dn * 2;
  __bf16* uvT = (__bf16*)q; q += (size_t)128 * Dn * 2;
  __bf16* ugT = (__bf16*)q; q += (size_t)128 * Dn * 2;
  __bf16* w2T = (__bf16*)q; q += (size_t)Dn * 128 * 2;
  __bf16* a2T = (__bf16*)q; q += (size_t)Dn * 128 * 2;
  __bf16* v2T = (__bf16*)q; q += (size_t)Dn * 128 * 2;
  __bf16* g2T = (__bf16*)q; q += (size_t)Dn * 128 * 2;
  float*  dot = (float*)q;  q += (size_t)Tn * Hn * 4;
  float*  WCg = (float*)q;  q += (size_t)NCH * Hn * 64 * 4;

  float* out     = (float*)d_out;
  float* out_xnl = out + (size_t)Tn * Dn;
  float* out_st  = out_xnl + Dn;

  castw3_kernel<<<dim3(4096, 3), 256, 0, stream>>>(W_r, W_k, W_v, Wr_b, Wk_b, Wv_b);
  castTU_kernel<<<dim3(2048, 5), 256, 0, stream>>>(
      w2, a2, v2, g2, w2T, a2T, v2T, g2T,
      w1, a1, v1, g1, uwT, uaT, uvT, ugT);
  lnmix_kernel<<<2048, 256, 0, stream>>>(
      x, state1, ln1_w, ln1_b, x_r, x_w, x_k, x_v, x_a, x_g,
      xr_b, xw_b, xk_b, xv_b, xa_b, xg_b, out_xnl);
  gemm37_kernel<<<dim3(16, 16, 7), 256, 0, stream>>>(
      xr_b, xk_b, xv_b, Wr_b, Wk_b, Wv_b, rbuf, kbuf, vbuf,
      xw_b, xa_b, xv_b, xg_b, uwT, uaT, uvT, ugT, yw, ya, yv, yg);
  cast1_kernel<<<4096, 256, 0, stream>>>(W_o, Wo_b);
  gemm_s2_kernel<<<dim3(16, 16, 4), 256, 0, stream>>>(
      yw, ya, yv, yg, w2T, a2T, v2T, g2T, w0, a0, v0, wdec, abuf, vbl, gbuf);
  prep_kernel<<<2048, 256, 0, stream>>>(rbuf, kbuf, vbuf, abuf, vbl, v_first,
                                        k_k, k_a, r_k, kkbuf, abbuf, dot);
  chunkA_kernel<<<dim3(NCH, Hn), 256, 0, stream>>>(
      wdec, kkbuf, abbuf, kbuf, rbuf,
      PAg, Rtil, BhatT, KhatT, PKg, Gbg, Gkg, WCg);
  vt_kernel<<<dim3(NCH, Hn), 256, 0, stream>>>(vbuf, Vt);
  chunkB_kernel<<<64, 256, 0, stream>>>(
      PAg, Rtil, BhatT, KhatT, PKg, Gbg, Gkg, WCg, Vt,
      state2, xobuf, out_st);
  post_kernel<<<2048, 256, 0, stream>>>(xobuf, vbuf, gbuf, dot, lnx_w, lnx_b, xo_b);
  gemm_wo_kernel<<<dim3(16, 16), 256, 0, stream>>>(xo_b, Wo_b, x, out);
}

// Round 16
// 346.247 us; speedup vs baseline: 1.1079x; 1.1079x over previous
//
#include <hip/hip_runtime.h>

#define Tn 2048
#define Dn 2048
#define Hn 32
#define Cn 32
#define NCH (Tn / Cn)

typedef float f32x4 __attribute__((ext_vector_type(4)));
typedef __bf16 bf16x8 __attribute__((ext_vector_type(8)));
typedef __bf16 bf16x4 __attribute__((ext_vector_type(4)));

// ---- fast wave-64 sum: DPP row reductions (VALU) + readlane ----
template <int CTRL>
__device__ __forceinline__ float dpp_add(float x) {
  int xi = __builtin_bit_cast(int, x);
  int sh = __builtin_amdgcn_update_dpp(0, xi, CTRL, 0xf, 0xf, true);
  return x + __builtin_bit_cast(float, sh);
}
__device__ __forceinline__ float rdlane(float x, int l) {
  int xi = __builtin_bit_cast(int, x);
  return __builtin_bit_cast(float, __builtin_amdgcn_readlane(xi, l));
}
__device__ __forceinline__ float waveSum(float v) {
  v = dpp_add<0x111>(v);
  v = dpp_add<0x112>(v);
  v = dpp_add<0x114>(v);
  v = dpp_add<0x118>(v);
  return (rdlane(v, 15) + rdlane(v, 31)) + (rdlane(v, 47) + rdlane(v, 63));
}

__device__ __forceinline__ float sigm(float x) { return 1.f / (1.f + expf(-x)); }

__device__ __forceinline__ void gl_lds16(const void* g, void* l) {
  __builtin_amdgcn_global_load_lds(
      (__attribute__((address_space(1))) void*)(g),
      (__attribute__((address_space(3))) void*)(l), 16, 0, 0);
}

// barrier that drains only LDS (lgkmcnt), leaving global loads in flight
__device__ __forceinline__ void bar_lgkm() {
  asm volatile("s_waitcnt lgkmcnt(0)" ::: "memory");
  __builtin_amdgcn_s_barrier();
}

__device__ __forceinline__ f32x4 mfma16(const __bf16* a, const __bf16* b, f32x4 acc) {
  return __builtin_amdgcn_mfma_f32_16x16x32_bf16(
      *(const bf16x8*)a, *(const bf16x8*)b, acc, 0, 0, 0);
}

// ---------------- weight casts ----------------

__global__ __launch_bounds__(256) void castw3_kernel(
    const float* __restrict__ A, const float* __restrict__ B,
    const float* __restrict__ C, __bf16* __restrict__ o0,
    __bf16* __restrict__ o1, __bf16* __restrict__ o2) {
  const int z = blockIdx.y;
  const float* src = z == 0 ? A : (z == 1 ? B : C);
  __bf16* dst = z == 0 ? o0 : (z == 1 ? o1 : o2);
  const size_t i4 = (size_t)blockIdx.x * 256 + threadIdx.x;
  f32x4 v = *(const f32x4*)(src + i4 * 4);
  bf16x4 o;
  o[0] = (__bf16)v[0]; o[1] = (__bf16)v[1]; o[2] = (__bf16)v[2]; o[3] = (__bf16)v[3];
  ((bf16x4*)dst)[i4] = o;
}

__global__ __launch_bounds__(256) void cast1_kernel(
    const float* __restrict__ src, __bf16* __restrict__ dst) {
  const size_t i4 = (size_t)blockIdx.x * 256 + threadIdx.x;
  f32x4 v = *(const f32x4*)(src + i4 * 4);
  bf16x4 o;
  o[0] = (__bf16)v[0]; o[1] = (__bf16)v[1]; o[2] = (__bf16)v[2]; o[3] = (__bf16)v[3];
  ((bf16x4*)dst)[i4] = o;
}

// y==0: stage-2 weights -> [D][128] padded; y=1..4: stage-1 -> [128][D] padded
__global__ __launch_bounds__(256) void castTU_kernel(
    const float* __restrict__ w2, const float* __restrict__ a2,
    const float* __restrict__ v2, const float* __restrict__ g2,
    __bf16* __restrict__ w2T, __bf16* __restrict__ a2T,
    __bf16* __restrict__ v2T, __bf16* __restrict__ g2T,
    const float* __restrict__ w1, const float* __restrict__ a1,
    const float* __restrict__ v1, const float* __restrict__ g1,
    __bf16* __restrict__ uwT, __bf16* __restrict__ uaT,
    __bf16* __restrict__ uvT, __bf16* __restrict__ ugT) {
  const int k = threadIdx.x;
  if (k >= 128) return;
  const int y = blockIdx.y;
  if (y == 0) {
    const int i = blockIdx.x;
    w2T[(size_t)i * 128 + k] = (k < 64) ? (__bf16)w2[(size_t)k * Dn + i] : (__bf16)0.f;
    a2T[(size_t)i * 128 + k] = (k < 64) ? (__bf16)a2[(size_t)k * Dn + i] : (__bf16)0.f;
    v2T[(size_t)i * 128 + k] = (k < 32) ? (__bf16)v2[(size_t)k * Dn + i] : (__bf16)0.f;
    g2T[(size_t)i * 128 + k] = (__bf16)g2[(size_t)k * Dn + i];
  } else {
    const int z = y - 1;
    const float* src = z == 0 ? w1 : (z == 1 ? a1 : (z == 2 ? v1 : g1));
    __bf16* dst = z == 0 ? uwT : (z == 1 ? uaT : (z == 2 ? uvT : ugT));
    const int R = z == 0 ? 64 : (z == 1 ? 64 : (z == 2 ? 32 : 128));
    const int d = blockIdx.x;
    dst[(size_t)k * Dn + d] = (k < R) ? (__bf16)src[(size_t)d * R + k] : (__bf16)0.f;
  }
}

// ---------------- fused ln1 + token-shift mix ----------------

__global__ __launch_bounds__(256) void lnmix_kernel(
    const float* __restrict__ x, const float* __restrict__ state1,
    const float* __restrict__ lw, const float* __restrict__ lb,
    const float* __restrict__ cr, const float* __restrict__ cw,
    const float* __restrict__ ck, const float* __restrict__ cv,
    const float* __restrict__ ca, const float* __restrict__ cg,
    __bf16* __restrict__ br, __bf16* __restrict__ bw, __bf16* __restrict__ bk,
    __bf16* __restrict__ bv, __bf16* __restrict__ ba, __bf16* __restrict__ bg,
    float* __restrict__ xn_last) {
  __shared__ float red[16];
  const int t = blockIdx.x, tid = threadIdx.x;
  const int lane = tid & 63, wv = tid >> 6;
  const float* xc = x + (size_t)t * Dn;
  const float* xp = x + (size_t)(t - 1) * Dn;
  float vc[8], vp[8];
  float sc = 0.f, sp = 0.f;
#pragma unroll
  for (int c = 0; c < 8; ++c) {
    vc[c] = xc[tid + c * 256]; sc += vc[c];
    vp[c] = (t > 0) ? xp[tid + c * 256] : 0.f; sp += vp[c];
  }
  sc = waveSum(sc); sp = waveSum(sp);
  if (lane == 0) { red[wv] = sc; red[8 + wv] = sp; }
  __syncthreads();
  const float mu_c = (red[0] + red[1] + red[2] + red[3]) * (1.f / (float)Dn);
  const float mu_p = (red[8] + red[9] + red[10] + red[11]) * (1.f / (float)Dn);
  float qc = 0.f, qp = 0.f;
#pragma unroll
  for (int c = 0; c < 8; ++c) {
    float d0 = vc[c] - mu_c; qc += d0 * d0;
    float d1 = vp[c] - mu_p; qp += d1 * d1;
  }
  qc = waveSum(qc); qp = waveSum(qp);
  if (lane == 0) { red[4 + wv] = qc; red[12 + wv] = qp; }
  __syncthreads();
  const float var_c = (red[4] + red[5] + red[6] + red[7]) * (1.f / (float)Dn);
  const float var_p = (red[12] + red[13] + red[14] + red[15]) * (1.f / (float)Dn);
  const float rstd_c = rsqrtf(var_c + 1e-5f);
  const float rstd_p = rsqrtf(var_p + 1e-5f);
#pragma unroll
  for (int c = 0; c < 8; ++c) {
    const int d = tid + c * 256;
    const size_t idx = (size_t)t * Dn + d;
    const float lwd = lw[d], lbd = lb[d];
    const float ync = (vc[c] - mu_c) * rstd_c * lwd + lbd;
    const float ynp = (t > 0) ? ((vp[c] - mu_p) * rstd_p * lwd + lbd) : state1[d];
    const float sx = ynp - ync;
    br[idx] = (__bf16)(ync + sx * cr[d]);
    bw[idx] = (__bf16)(ync + sx * cw[d]);
    bk[idx] = (__bf16)(ync + sx * ck[d]);
    bv[idx] = (__bf16)(ync + sx * cv[d]);
    ba[idx] = (__bf16)(ync + sx * ca[d]);
    bg[idx] = (__bf16)(ync + sx * cg[d]);
    if (t == Tn - 1) xn_last[d] = ync;
  }
}

// ---------------- MFMA GEMM tile core: single-buffer, BK=64, XOR-swizzled ----------------
// LDS [128][64] linear dest for global_load_lds; bank-conflict fix via
// pre-swizzled GLOBAL source unit (u ^= row&7) + matching swizzled read
// (guide T2 / m201-m173 both-sides pattern). 2-way residual conflict (free).

__device__ __forceinline__ void gemm_tile(const __bf16* __restrict__ A,
                                          const __bf16* __restrict__ B,
                                          int K, int row0, int col0,
                                          f32x4 (&acc)[4][4]) {
  __shared__ __attribute__((aligned(16))) __bf16 As[8192];
  __shared__ __attribute__((aligned(16))) __bf16 Bs[8192];
  const int tid = threadIdx.x;
  const int lane = tid & 63, wid = tid >> 6;
  const int wm = (wid >> 1) * 64, wn = (wid & 1) * 64;
  const int lr = lane & 15, lg = lane >> 4;
  for (int kt = 0; kt < K; kt += 64) {
#pragma unroll
    for (int it = 0; it < 4; ++it) {
      const int L = it * 256 + tid;
      const int rr = L >> 3;                  // row 0..127
      const int usw = (L & 7) ^ (rr & 7);     // swizzled 16B-unit in global
      const int lb = (it * 256 + wid * 64) * 8;   // linear LDS dest
      gl_lds16(A + (size_t)(row0 + rr) * K + (kt + usw * 8), &As[lb]);
      gl_lds16(B + (size_t)(col0 + rr) * K + (kt + usw * 8), &Bs[lb]);
    }
    __syncthreads();
#pragma unroll
    for (int ks = 0; ks < 2; ++ks) {
      bf16x8 af[4], bfv[4];
#pragma unroll
      for (int mf = 0; mf < 4; ++mf) {
        const int r = wm + mf * 16 + lr;
        af[mf] = *(const bf16x8*)&As[r * 64 + (((ks * 4 + lg) ^ (lr & 7)) * 8)];
      }
#pragma unroll
      for (int nf = 0; nf < 4; ++nf) {
        const int r = wn + nf * 16 + lr;
        bfv[nf] = *(const bf16x8*)&Bs[r * 64 + (((ks * 4 + lg) ^ (lr & 7)) * 8)];
      }
#pragma unroll
      for (int mf = 0; mf < 4; ++mf)
#pragma unroll
        for (int nf = 0; nf < 4; ++nf)
          acc[mf][nf] = __builtin_amdgcn_mfma_f32_16x16x32_bf16(
              af[mf], bfv[nf], acc[mf][nf], 0, 0, 0);
    }
    __syncthreads();
  }
}

// XCD region swizzle for 16x16 grids: each XCD owns a 4x8 tile region
__device__ __forceinline__ void xcd_swz16(int& bx, int& by) {
  const int lid = bx + (by << 4);
  const int xcd = lid & 7, idx = lid >> 3;
  bx = ((xcd & 3) << 2) + (idx & 3);
  by = ((xcd >> 2) << 3) + (idx >> 2);
}

// r/k/v (z=0..2, full y-grid, swizzled) + LoRA stage-1 (z=3..6, y==0 only)
__global__ __launch_bounds__(256) void gemm37_kernel(
    const __bf16* __restrict__ A0, const __bf16* __restrict__ A1,
    const __bf16* __restrict__ A2, const __bf16* __restrict__ B0,
    const __bf16* __restrict__ B1, const __bf16* __restrict__ B2,
    __bf16* __restrict__ C0, __bf16* __restrict__ C1, __bf16* __restrict__ C2,
    const __bf16* __restrict__ Aw, const __bf16* __restrict__ Aa,
    const __bf16* __restrict__ Av, const __bf16* __restrict__ Ag,
    const __bf16* __restrict__ Bw, const __bf16* __restrict__ Ba,
    const __bf16* __restrict__ Bv, const __bf16* __restrict__ Bg,
    __bf16* __restrict__ Cw, __bf16* __restrict__ Ca,
    __bf16* __restrict__ Cv, __bf16* __restrict__ Cg) {
  const int z = blockIdx.z;
  if (z >= 3 && blockIdx.y != 0) return;
  const __bf16* A; const __bf16* B; __bf16* C;
  switch (z) {
    case 0: A = A0; B = B0; C = C0; break;
    case 1: A = A1; B = B1; C = C1; break;
    case 2: A = A2; B = B2; C = C2; break;
    case 3: A = Aw; B = Bw; C = Cw; break;
    case 4: A = Aa; B = Ba; C = Ca; break;
    case 5: A = Av; B = Bv; C = Cv; break;
    default: A = Ag; B = Bg; C = Cg; break;
  }
  int bx = blockIdx.x, by = blockIdx.y;
  if (z < 3) xcd_swz16(bx, by);
  const int row0 = bx * 128, col0 = (z < 3) ? by * 128 : 0;
  const int ldc = (z < 3) ? Dn : 128;
  f32x4 acc[4][4] = {};
  gemm_tile(A, B, Dn, row0, col0, acc);
  const int lane = threadIdx.x & 63, wid = threadIdx.x >> 6;
  const int wm = (wid >> 1) * 64, wn = (wid & 1) * 64;
#pragma unroll
  for (int mf = 0; mf < 4; ++mf) {
    const int r0 = row0 + wm + mf * 16 + ((lane >> 4) << 2);
#pragma unroll
    for (int nf = 0; nf < 4; ++nf) {
      const int c0 = col0 + wn + nf * 16 + (lane & 15);
#pragma unroll
      for (int rg = 0; rg < 4; ++rg) {
        float val = acc[mf][nf][rg];
        if (z == 3)      val = tanhf(val);
        else if (z == 6) val = sigm(val);
        C[(size_t)(r0 + rg) * ldc + c0] = (__bf16)val;
      }
    }
  }
}

// LoRA stage-2 fused, uniform K=128 (zero-padded)
__global__ __launch_bounds__(256) void gemm_s2_kernel(
    const __bf16* __restrict__ Aw, const __bf16* __restrict__ Aa,
    const __bf16* __restrict__ Av, const __bf16* __restrict__ Ag,
    const __bf16* __restrict__ Bw, const __bf16* __restrict__ Ba,
    const __bf16* __restrict__ Bv, const __bf16* __restrict__ Bg,
    const float* __restrict__ w0, const float* __restrict__ a0,
    const float* __restrict__ v0, __bf16* __restrict__ Cw,
    __bf16* __restrict__ Ca, __bf16* __restrict__ Cv, __bf16* __restrict__ Cg) {
  const int z = blockIdx.z;
  const __bf16* A = z == 0 ? Aw : (z == 1 ? Aa : (z == 2 ? Av : Ag));
  const __bf16* B = z == 0 ? Bw : (z == 1 ? Ba : (z == 2 ? Bv : Bg));
  const float* bias = z == 0 ? w0 : (z == 1 ? a0 : (z == 2 ? v0 : (const float*)0));
  __bf16* C = z == 0 ? Cw : (z == 1 ? Ca : (z == 2 ? Cv : Cg));
  const int row0 = blockIdx.x * 128, col0 = blockIdx.y * 128;
  f32x4 acc[4][4] = {};
  gemm_tile(A, B, 128, row0, col0, acc);
  const int lane = threadIdx.x & 63, wid = threadIdx.x >> 6;
  const int wm = (wid >> 1) * 64, wn = (wid & 1) * 64;
#pragma unroll
  for (int mf = 0; mf < 4; ++mf) {
    const int r0 = row0 + wm + mf * 16 + ((lane >> 4) << 2);
#pragma unroll
    for (int nf = 0; nf < 4; ++nf) {
      const int c0 = col0 + wn + nf * 16 + (lane & 15);
#pragma unroll
      for (int rg = 0; rg < 4; ++rg) {
        float val = acc[mf][nf][rg];
        if (z == 0)      val = expf(-0.606531f * sigm(val + bias[c0]));
        else if (z < 3)  val = sigm(val + bias[c0]);
        C[(size_t)(r0 + rg) * Dn + c0] = (__bf16)val;
      }
    }
  }
}

__global__ __launch_bounds__(256) void gemm_wo_kernel(
    const __bf16* __restrict__ A, const __bf16* __restrict__ B,
    const float* __restrict__ xres, float* __restrict__ C) {
  int bx = blockIdx.x, by = blockIdx.y;
  xcd_swz16(bx, by);
  const int row0 = bx * 128, col0 = by * 128;
  f32x4 acc[4][4] = {};
  gemm_tile(A, B, Dn, row0, col0, acc);
  const int lane = threadIdx.x & 63, wid = threadIdx.x >> 6;
  const int wm = (wid >> 1) * 64, wn = (wid & 1) * 64;
#pragma unroll
  for (int mf = 0; mf < 4; ++mf) {
    const int r0 = row0 + wm + mf * 16 + ((lane >> 4) << 2);
#pragma unroll
    for (int nf = 0; nf < 4; ++nf) {
      const int c0 = col0 + wn + nf * 16 + (lane & 15);
#pragma unroll
      for (int rg = 0; rg < 4; ++rg)
        C[(size_t)(r0 + rg) * Dn + c0] =
            acc[mf][nf][rg] + xres[(size_t)(r0 + rg) * Dn + c0];
    }
  }
}

// ---------------- prep ----------------

__global__ __launch_bounds__(256) void prep_kernel(
    const __bf16* __restrict__ r, __bf16* __restrict__ k, __bf16* __restrict__ v,
    const __bf16* __restrict__ a, const __bf16* __restrict__ vb,
    const float* __restrict__ v_first, const float* __restrict__ k_k,
    const float* __restrict__ k_a, const float* __restrict__ r_k,
    __bf16* __restrict__ kk_out, __bf16* __restrict__ ab_out,
    float* __restrict__ dot_out) {
  const int t = blockIdx.x;
  const int lane = threadIdx.x & 63, wv = threadIdx.x >> 6;
#pragma unroll 1
  for (int c = 0; c < 8; ++c) {
    const int d = c * 256 + wv * 64 + lane;
    const size_t idx = (size_t)t * Dn + d;
    const float kvv = (float)k[idx];
    const float kh = kvv * k_k[d];
    const float nrm = sqrtf(waveSum(kh * kh)) + 1e-6f;
    const float kkv = kh / nrm;
    const float av = (float)a[idx];
    float vv = (float)v[idx];
    vv = vv + (v_first[idx] - vv) * (float)vb[idx];
    const float kfv = kvv * (1.f + (av - 1.f) * k_a[d]);
    const float dt = waveSum((float)r[idx] * kfv * r_k[d]);
    kk_out[idx] = (__bf16)kkv;
    ab_out[idx] = (__bf16)(kkv * av);
    k[idx] = (__bf16)kfv;
    v[idx] = (__bf16)vv;
    if (lane == 0) dot_out[t * Hn + (d >> 6)] = dt;
  }
}

// ---------------- chunkA: all matrix products on MFMA ----------------

__global__ __launch_bounds__(256) void chunkA_kernel(
    const __bf16* __restrict__ wd, const __bf16* __restrict__ kk,
    const __bf16* __restrict__ ab, const __bf16* __restrict__ kf,
    const __bf16* __restrict__ r,
    __bf16* __restrict__ PAg, __bf16* __restrict__ Rtil,
    __bf16* __restrict__ BhatT, __bf16* __restrict__ KhatT,
    __bf16* __restrict__ PKg,
    __bf16* __restrict__ Gbg, __bf16* __restrict__ Gkg,
    float* __restrict__ WCg) {
  const int c = blockIdx.x, h = blockIdx.y;
  const int tid = threadIdx.x;
  const int lane = tid & 63, wid = tid >> 6;
  const int lr = lane & 15, lg = lane >> 4, lk = lg * 8;
  __shared__ __attribute__((aligned(16))) __bf16 A_l[32][72];
  __shared__ __attribute__((aligned(16))) __bf16 B_l[32][72], K_l[32][72], R_l[32][72];
  __shared__ __attribute__((aligned(16))) __bf16 At_t[64][40];
  __shared__ float W_l[33][64];
  __shared__ __attribute__((aligned(16))) __bf16 Mn[32][40], Mt[32][40], Mkat[32][40];
  __shared__ __attribute__((aligned(16))) __bf16 Pa[32][40], Pb[32][40];
  __shared__ __attribute__((aligned(16))) __bf16 Tn_[32][40], Tt_[32][40];
  __shared__ __attribute__((aligned(16))) __bf16 Un_[32][40], Ut_[32][40];

  const size_t rowbase = (size_t)(c * Cn) * Dn + (size_t)h * 64;
  const int tt = tid >> 3, j0 = (tid & 7) * 8;
  const size_t g = rowbase + (size_t)tt * Dn + j0;
  *(bf16x8*)&A_l[tt][j0] = *(const bf16x8*)(wd + g);
  __syncthreads();
  if (tid < 64) {
    const int j = tid;
    float cur = 1.f;
    W_l[0][j] = 1.f;
    for (int t = 0; t < Cn; ++t) {
      cur *= (float)A_l[t][j];
      W_l[t + 1][j] = cur;
    }
    WCg[((size_t)c * Hn + h) * 64 + j] = cur;
  }
  __syncthreads();
  {
    bf16x8 kkv = *(const bf16x8*)(kk + g);
    bf16x8 abv = *(const bf16x8*)(ab + g);
    bf16x8 kv  = *(const bf16x8*)(kf + g);
    bf16x8 rv  = *(const bf16x8*)(r + g);
    bf16x8 oa, ob, ok, orr;
    const size_t tb = ((size_t)c * Hn + h) * 2048;
#pragma unroll
    for (int e = 0; e < 8; ++e) {
      const int j = j0 + e;
      const float Wexc = W_l[tt][j], Winc = W_l[tt + 1][j], WC = W_l[32][j];
      const float inv = 1.f / Winc;
      const float at = -(float)kkv[e] * Wexc;
      const float bt = (float)abv[e] * inv;
      const float kt = (float)kv[e] * inv;
      const float rt = (float)rv[e] * Winc;
      oa[e] = (__bf16)at; ob[e] = (__bf16)bt; ok[e] = (__bf16)kt;
      orr[e] = (__bf16)rt;
      At_t[j][tt] = (__bf16)at;
      BhatT[tb + (size_t)j * 32 + tt] = (__bf16)(bt * WC);
      KhatT[tb + (size_t)j * 32 + tt] = (__bf16)(kt * WC);
    }
    *(bf16x8*)&A_l[tt][j0] = oa;
    *(bf16x8*)&B_l[tt][j0] = ob;
    *(bf16x8*)&K_l[tt][j0] = ok;
    *(bf16x8*)&R_l[tt][j0] = orr;
    *(bf16x8*)(Rtil + g) = orr;
  }
  __syncthreads();
  const size_t matbase = ((size_t)c * Hn + h) * (Cn * Cn);
  {
    const __bf16 (*Ax)[72] = (wid < 2) ? A_l : R_l;
    const __bf16 (*Bx)[72] = ((wid & 1) == 0) ? B_l : K_l;
#pragma unroll
    for (int tile = 0; tile < 4; ++tile) {
      const int tm = (tile >> 1) * 16, tn = (tile & 1) * 16;
      f32x4 acc = {};
      acc = mfma16(&Ax[tm + lr][lk], &Bx[tn + lr][lk], acc);
      acc = mfma16(&Ax[tm + lr][32 + lk], &Bx[tn + lr][32 + lk], acc);
      const int col = tn + lr;
#pragma unroll
      for (int e = 0; e < 4; ++e) {
        const int row = tm + lg * 4 + e;
        if (wid == 0) {
          const __bf16 v = (__bf16)((col < row) ? acc[e] : 0.f);
          Mn[row][col] = v; Mt[col][row] = v;
        } else if (wid == 1) {
          Mkat[col][row] = (__bf16)((col < row) ? acc[e] : 0.f);
        } else if (wid == 2) {
          Gbg[matbase + row * 32 + col] = (__bf16)((col <= row) ? acc[e] : 0.f);
        } else {
          Gkg[matbase + row * 32 + col] = (__bf16)((col <= row) ? acc[e] : 0.f);
        }
      }
    }
  }
  __syncthreads();
  for (int rep = 0; rep < 4; ++rep) {
    const int id = rep * 256 + tid;
    const int t = id >> 5, ta = id & 31;
    Pa[t][ta] = (__bf16)((float)Mn[t][ta] + (t == ta ? 1.f : 0.f));
  }
  __syncthreads();
  const int tm = (wid >> 1) * 16, tn = (wid & 1) * 16;
  auto sq = [&](__bf16 (*Dn_)[40], __bf16 (*Dt_)[40],
                __bf16 (*Xn)[40], __bf16 (*Xt)[40]) {
    f32x4 acc = {};
    acc = mfma16(&Xn[tm + lr][lk], &Xt[tn + lr][lk], acc);
    const int col = tn + lr;
#pragma unroll
    for (int e = 0; e < 4; ++e) {
      const int row = tm + lg * 4 + e;
      const __bf16 v = (__bf16)acc[e];
      Dn_[row][col] = v; Dt_[col][row] = v;
    }
    __syncthreads();
  };
  auto pup = [&](__bf16 (*Dn_)[40], __bf16 (*Pn)[40], __bf16 (*Tt)[40]) {
    f32x4 acc;
    const int col = tn + lr;
#pragma unroll
    for (int e = 0; e < 4; ++e) acc[e] = (float)Pn[tm + lg * 4 + e][col];
    acc = mfma16(&Pn[tm + lr][lk], &Tt[tn + lr][lk], acc);
#pragma unroll
    for (int e = 0; e < 4; ++e) Dn_[tm + lg * 4 + e][col] = (__bf16)acc[e];
    __syncthreads();
  };
  sq(Tn_, Tt_, Mn, Mt);
  pup(Pb, Pa, Tt_);
  sq(Un_, Ut_, Tn_, Tt_);
  pup(Pa, Pb, Ut_);
  sq(Tn_, Tt_, Un_, Ut_);
  pup(Pb, Pa, Tt_);
  sq(Un_, Ut_, Tn_, Tt_);
  pup(Pa, Pb, Ut_);
  {
    f32x4 acc = {};
    acc = mfma16(&Pa[tm + lr][lk], &Mkat[tn + lr][lk], acc);
    const int col = tn + lr;
#pragma unroll
    for (int e = 0; e < 4; ++e)
      PKg[matbase + (tm + lg * 4 + e) * 32 + col] = (__bf16)acc[e];
  }
#pragma unroll
  for (int half = 0; half < 2; ++half) {
    const int jn = (wid & 1) * 16 + half * 32;
    f32x4 acc = {};
    acc = mfma16(&Pa[tm + lr][lk], &At_t[jn + lr][lk], acc);
    const int col = jn + lr;
#pragma unroll
    for (int e = 0; e < 4; ++e)
      PAg[rowbase + (size_t)(tm + lg * 4 + e) * Dn + col] = (__bf16)acc[e];
  }
}

// ---------------- vt: vbuf [t][D] -> Vt [c][h][i][t] ----------------

__global__ __launch_bounds__(256) void vt_kernel(
    const __bf16* __restrict__ vbuf, __bf16* __restrict__ Vt) {
  const int c = blockIdx.x, h = blockIdx.y;
  __shared__ __bf16 tile[32][72];
  const int tid = threadIdx.x;
  {
    const int t = tid >> 3, i0 = (tid & 7) * 8;
    *(bf16x8*)&tile[t][i0] =
        *(const bf16x8*)(vbuf + (size_t)(c * Cn + t) * Dn + h * 64 + i0);
  }
  __syncthreads();
  {
    const int i = tid >> 2, t0 = (tid & 3) * 8;
    bf16x8 o;
#pragma unroll
    for (int e = 0; e < 8; ++e) o[e] = tile[t0 + e][i];
    *(bf16x8*)(Vt + ((size_t)c * Hn + h) * 2048 + (size_t)i * 32 + t0) = o;
  }
}

// ---------------- chunkB: MFMA, 2 compute phases (PA-fused), 64 blocks ----------------

__global__ __launch_bounds__(256) void chunkB_kernel(
    const __bf16* __restrict__ PAg, const __bf16* __restrict__ Rtil,
    const __bf16* __restrict__ BhatT, const __bf16* __restrict__ KhatT,
    const __bf16* __restrict__ PKg,
    const __bf16* __restrict__ Gbg, const __bf16* __restrict__ Gkg,
    const float* __restrict__ WCg, const __bf16* __restrict__ Vt,
    const float* __restrict__ st_in, __bf16* __restrict__ xo,
    float* __restrict__ st_out) {
  const int b = blockIdx.x;
  const int xcd = b & 7, rest = b >> 3;
  const int h = xcd * 4 + (rest & 3);
  const int io = (rest >> 2) * 32;
  const int tid = threadIdx.x;
  const int lane = tid & 63, wid = tid >> 6;
  const int lr = lane & 15, lg = lane >> 4;
  const int lk = lg * 8;

  __shared__ __attribute__((aligned(16))) float S_l[32][68];
  __shared__ __attribute__((aligned(16))) __bf16 Sb_l[32][72];
  __shared__ __attribute__((aligned(16))) __bf16 PA_l[32][72], R_l[32][72];
  __shared__ __attribute__((aligned(16))) __bf16 BhT_l[64][40], KhT_l[64][40];
  __shared__ __attribute__((aligned(16))) __bf16 Vt_l[32][40];
  __shared__ __attribute__((aligned(16))) __bf16 PK_l[32][40];
  __shared__ __attribute__((aligned(16))) __bf16 Gb_l[32][40], Gk_l[32][40];
  __shared__ __attribute__((aligned(16))) __bf16 SA_l[32][40];
  __shared__ float WC_l[64];

  {
    const int i = tid >> 3, j0 = (tid & 7) * 8;
    const float* src = st_in + (size_t)h * 4096 + (size_t)(io + i) * 64 + j0;
    *(f32x4*)&S_l[i][j0] = *(const f32x4*)src;
    *(f32x4*)&S_l[i][j0 + 4] = *(const f32x4*)(src + 4);
  }

  bf16x8 rPA, rR, rBh, rKh;
  bf16x4 rV, rPK, rGb, rGk;
  float rWC = 0.f;

  auto load_regs = [&](int c) {
    const size_t rb = (size_t)(c * Cn) * Dn + (size_t)h * 64;
    {
      const int t = tid >> 3, j0 = (tid & 7) * 8;
      rPA = *(const bf16x8*)(PAg + rb + (size_t)t * Dn + j0);
      rR  = *(const bf16x8*)(Rtil + rb + (size_t)t * Dn + j0);
    }
    const size_t tb = ((size_t)c * Hn + h) * 2048;
    {
      const int jj = tid >> 2, t0 = (tid & 3) * 8;
      rBh = *(const bf16x8*)(BhatT + tb + (size_t)jj * 32 + t0);
      rKh = *(const bf16x8*)(KhatT + tb + (size_t)jj * 32 + t0);
    }
    {
      const int i = tid >> 3, t0 = (tid & 7) * 4;
      rV = *(const bf16x4*)(Vt + tb + (size_t)(io + i) * 32 + t0);
    }
    const size_t mb = ((size_t)c * Hn + h) * 1024 + (size_t)tid * 4;
    rPK = *(const bf16x4*)(PKg + mb);
    rGb = *(const bf16x4*)(Gbg + mb);
    rGk = *(const bf16x4*)(Gkg + mb);
    if (tid < 64) rWC = WCg[((size_t)c * Hn + h) * 64 + tid];
  };
  auto store_lds = [&]() {
    {
      const int t = tid >> 3, j0 = (tid & 7) * 8;
      *(bf16x8*)&PA_l[t][j0] = rPA;
      *(bf16x8*)&R_l[t][j0] = rR;
    }
    {
      const int jj = tid >> 2, t0 = (tid & 3) * 8;
      *(bf16x8*)&BhT_l[jj][t0] = rBh;
      *(bf16x8*)&KhT_l[jj][t0] = rKh;
    }
    {
      const int i = tid >> 3, t0 = (tid & 7) * 4;
      *(bf16x4*)&Vt_l[i][t0] = rV;
    }
    {
      const int t = tid >> 3, u0 = (tid & 7) * 4;
      *(bf16x4*)&PK_l[t][u0] = rPK;
      *(bf16x4*)&Gb_l[t][u0] = rGb;
      *(bf16x4*)&Gk_l[t][u0] = rGk;
    }
    if (tid < 64) WC_l[tid] = rWC;
  };
  auto sb_refresh = [&]() {
    const int i = tid >> 3, j0 = (tid & 7) * 8;
    bf16x8 o;
#pragma unroll
    for (int e = 0; e < 8; ++e) o[e] = (__bf16)S_l[i][j0 + e];
    *(bf16x8*)&Sb_l[i][j0] = o;
  };

  load_regs(0);
  store_lds();
  sb_refresh();
  bar_lgkm();

  const int tm = (wid >> 1) * 16, tn = (wid & 1) * 16;

#pragma unroll 1
  for (int c = 0; c < NCH; ++c) {
    load_regs(c + 1 < NCH ? c + 1 : c);
    // SA = PA*Sb^T + PK*V
    {
      f32x4 acc = {};
      acc = mfma16(&PA_l[tm + lr][lk], &Sb_l[tn + lr][lk], acc);
      acc = mfma16(&PA_l[tm + lr][32 + lk], &Sb_l[tn + lr][32 + lk], acc);
      acc = mfma16(&PK_l[tm + lr][lk], &Vt_l[tn + lr][lk], acc);
      bf16x4 o;
#pragma unroll
      for (int e = 0; e < 4; ++e) o[e] = (__bf16)acc[e];
      *(bf16x4*)&SA_l[tn + lr][tm + lg * 4] = o;
    }
    bar_lgkm();
    // O = Gb*SA + Gk*V + Rtil*Sb^T
    {
      f32x4 acc = {};
      acc = mfma16(&Gb_l[tm + lr][lk], &SA_l[tn + lr][lk], acc);
      acc = mfma16(&Gk_l[tm + lr][lk], &Vt_l[tn + lr][lk], acc);
      acc = mfma16(&R_l[tm + lr][lk], &Sb_l[tn + lr][lk], acc);
      acc = mfma16(&R_l[tm + lr][32 + lk], &Sb_l[tn + lr][32 + lk], acc);
      const int ig = h * 64 + io + tn + lr;
#pragma unroll
      for (int e = 0; e < 4; ++e)
        xo[(size_t)(c * Cn + tm + lg * 4 + e) * Dn + ig] = (__bf16)acc[e];
    }
    // S' = S.*WC + SA^T*Bh + V^T*Kh
#pragma unroll
    for (int tt2 = 0; tt2 < 2; ++tt2) {
      const int tix = wid + tt2 * 4;
      const int im = (tix & 1) * 16, jn = (tix >> 1) * 16;
      const float wc = WC_l[jn + lr];
      f32x4 acc;
#pragma unroll
      for (int e = 0; e < 4; ++e) acc[e] = S_l[im + lg * 4 + e][jn + lr] * wc;
      acc = mfma16(&SA_l[im + lr][lk], &BhT_l[jn + lr][lk], acc);
      acc = mfma16(&Vt_l[im + lr][lk], &KhT_l[jn + lr][lk], acc);
#pragma unroll
      for (int e = 0; e < 4; ++e) S_l[im + lg * 4 + e][jn + lr] = acc[e];
    }
    bar_lgkm();
    store_lds();
    sb_refresh();
    bar_lgkm();
  }
  {
    const int i = tid >> 3, j0 = (tid & 7) * 8;
    float* dst = st_out + (size_t)h * 4096 + (size_t)(io + i) * 64 + j0;
    *(f32x4*)dst = *(const f32x4*)&S_l[i][j0];
    *(f32x4*)(dst + 4) = *(const f32x4*)&S_l[i][j0 + 4];
  }
}

// ---------------- post ----------------

__global__ __launch_bounds__(256) void post_kernel(
    const __bf16* __restrict__ xo, const __bf16* __restrict__ v,
    const __bf16* __restrict__ g, const float* __restrict__ dot,
    const float* __restrict__ lnw, const float* __restrict__ lnb,
    __bf16* __restrict__ out) {
  const int t = blockIdx.x;
  const int lane = threadIdx.x & 63, wv = threadIdx.x >> 6;
#pragma unroll 1
  for (int c = 0; c < 8; ++c) {
    const int d = c * 256 + wv * 64 + lane;
    const size_t idx = (size_t)t * Dn + d;
    const float val = (float)xo[idx];
    const float mu = waveSum(val) * (1.f / 64.f);
    const float ctr = val - mu;
    const float var = waveSum(ctr * ctr) * (1.f / 64.f);
    float y = ctr * rsqrtf(var + 0.00064f);
    y = y * lnw[d] + lnb[d];
    const float res = (y + dot[t * Hn + (d >> 6)] * (float)v[idx]) * (float)g[idx];
    out[idx] = (__bf16)res;
  }
}

// ---------------- launcher ----------------

extern "C" void kernel_launch(void* const* d_in, const int* in_sizes, int n_in,
                              void* d_out, int out_size, void* d_ws, size_t ws_size,
                              hipStream_t stream) {
  (void)in_sizes; (void)n_in; (void)out_size; (void)ws_size;
  const float* x       = (const float*)d_in[0];
  const float* state1  = (const float*)d_in[1];
  const float* state2  = (const float*)d_in[2];
  const float* v_first = (const float*)d_in[3];
  const float* ln1_w   = (const float*)d_in[4];
  const float* ln1_b   = (const float*)d_in[5];
  const float* x_r     = (const float*)d_in[6];
  const float* x_w     = (const float*)d_in[7];
  const float* x_k     = (const float*)d_in[8];
  const float* x_v     = (const float*)d_in[9];
  const float* x_a     = (const float*)d_in[10];
  const float* x_g     = (const float*)d_in[11];
  const float* W_r     = (const float*)d_in[12];
  const float* W_k     = (const float*)d_in[13];
  const float* W_v     = (const float*)d_in[14];
  const float* W_o     = (const float*)d_in[15];
  const float* w1      = (const float*)d_in[16];
  const float* w2      = (const float*)d_in[17];
  const float* w0      = (const float*)d_in[18];
  const float* a1      = (const float*)d_in[19];
  const float* a2      = (const float*)d_in[20];
  const float* a0      = (const float*)d_in[21];
  const float* v1      = (const float*)d_in[22];
  const float* v2      = (const float*)d_in[23];
  const float* v0      = (const float*)d_in[24];
  const float* g1      = (const float*)d_in[25];
  const float* g2      = (const float*)d_in[26];
  const float* k_k     = (const float*)d_in[27];
  const float* k_a     = (const float*)d_in[28];
  const float* r_k     = (const float*)d_in[29];
  const float* lnx_w   = (const float*)d_in[30];
  const float* lnx_b   = (const float*)d_in[31];

  char* p = (char*)d_ws;
  const size_t MB = 1ull << 20;
  __bf16* PAg   = (__bf16*)(p + 0 * MB);
  __bf16* xr_b  = (__bf16*)(p + 8 * MB);
  __bf16* Wo_b  = (__bf16*)(p + 8 * MB);
  __bf16* xw_b  = (__bf16*)(p + 16 * MB);
  __bf16* wdec  = (__bf16*)(p + 16 * MB);
  __bf16* xo_b  = (__bf16*)(p + 16 * MB);
  __bf16* xk_b  = (__bf16*)(p + 24 * MB);
  __bf16* abuf  = (__bf16*)(p + 24 * MB);
  __bf16* Rtil  = (__bf16*)(p + 24 * MB);
  __bf16* xv_b  = (__bf16*)(p + 32 * MB);
  __bf16* vbl   = (__bf16*)(p + 32 * MB);
  __bf16* BhatT = (__bf16*)(p + 32 * MB);
  __bf16* xa_b  = (__bf16*)(p + 40 * MB);
  __bf16* gbuf  = (__bf16*)(p + 40 * MB);
  __bf16* xg_b  = (__bf16*)(p + 48 * MB);
  __bf16* kkbuf = (__bf16*)(p + 48 * MB);
  __bf16* xobuf = (__bf16*)(p + 48 * MB);
  __bf16* Wr_b  = (__bf16*)(p + 56 * MB);
  __bf16* abbuf = (__bf16*)(p + 56 * MB);
  __bf16* Wk_b  = (__bf16*)(p + 64 * MB);
  __bf16* KhatT = (__bf16*)(p + 64 * MB);
  __bf16* Wv_b  = (__bf16*)(p + 72 * MB);
  __bf16* PKg   = (__bf16*)(p + 72 * MB);
  __bf16* rbuf  = (__bf16*)(p + 80 * MB);
  __bf16* kbuf  = (__bf16*)(p + 88 * MB);
  __bf16* Vt    = (__bf16*)(p + 88 * MB);   // kbuf dead after chunkA
  __bf16* vbuf  = (__bf16*)(p + 96 * MB);
  __bf16* Gbg   = (__bf16*)(p + 104 * MB);
  __bf16* Gkg   = (__bf16*)(p + 108 * MB);
  char* q = p + 112 * MB;
  __bf16* yw  = (__bf16*)q; q += (size_t)Tn * 128 * 2;
  __bf16* ya  = (__bf16*)q; q += (size_t)Tn * 128 * 2;
  __bf16* yv  = (__bf16*)q; q += (size_t)Tn * 128 * 2;
  __bf16* yg  = (__bf16*)q; q += (size_t)Tn * 128 * 2;
  __bf16* uwT = (__bf16*)q; q += (size_t)128 * Dn * 2;
  __bf16* uaT = (__bf16*)q; q += (size_t)128 * Dn * 2;
  __bf16* uvT = (__bf16*)q; q += (size_t)128 * Dn * 2;
  __bf16* ugT = (__bf16*)q; q += (size_t)128 * Dn * 2;
  __bf16* w2T = (__bf16*)q; q += (size_t)Dn * 128 * 2;
  __bf16* a2T = (__bf16*)q; q += (size_t)Dn * 128 * 2;
  __bf16* v2T = (__bf16*)q; q += (size_t)Dn * 128 * 2;
  __bf16* g2T = (__bf16*)q; q += (size_t)Dn * 128 * 2;
  float*  dot = (float*)q;  q += (size_t)Tn * Hn * 4;
  float*  WCg = (float*)q;  q += (size_t)NCH * Hn * 64 * 4;

  float* out     = (float*)d_out;
  float* out_xnl = out + (size_t)Tn * Dn;
  float* out_st  = out_xnl + Dn;

  castw3_kernel<<<dim3(4096, 3), 256, 0, stream>>>(W_r, W_k, W_v, Wr_b, Wk_b, Wv_b);
  castTU_kernel<<<dim3(2048, 5), 256, 0, stream>>>(
      w2, a2, v2, g2, w2T, a2T, v2T, g2T,
      w1, a1, v1, g1, uwT, uaT, uvT, ugT);
  lnmix_kernel<<<2048, 256, 0, stream>>>(
      x, state1, ln1_w, ln1_b, x_r, x_w, x_k, x_v, x_a, x_g,
      xr_b, xw_b, xk_b, xv_b, xa_b, xg_b, out_xnl);
  gemm37_kernel<<<dim3(16, 16, 7), 256, 0, stream>>>(
      xr_b, xk_b, xv_b, Wr_b, Wk_b, Wv_b, rbuf, kbuf, vbuf,
      xw_b, xa_b, xv_b, xg_b, uwT, uaT, uvT, ugT, yw, ya, yv, yg);
  cast1_kernel<<<4096, 256, 0, stream>>>(W_o, Wo_b);
  gemm_s2_kernel<<<dim3(16, 16, 4), 256, 0, stream>>>(
      yw, ya, yv, yg, w2T, a2T, v2T, g2T, w0, a0, v0, wdec, abuf, vbl, gbuf);
  prep_kernel<<<2048, 256, 0, stream>>>(rbuf, kbuf, vbuf, abuf, vbl, v_first,
                                        k_k, k_a, r_k, kkbuf, abbuf, dot);
  chunkA_kernel<<<dim3(NCH, Hn), 256, 0, stream>>>(
      wdec, kkbuf, abbuf, kbuf, rbuf,
      PAg, Rtil, BhatT, KhatT, PKg, Gbg, Gkg, WCg);
  vt_kernel<<<dim3(NCH, Hn), 256, 0, stream>>>(vbuf, Vt);
  chunkB_kernel<<<64, 256, 0, stream>>>(
      PAg, Rtil, BhatT, KhatT, PKg, Gbg, Gkg, WCg, Vt,
      state2, xobuf, out_st);
  post_kernel<<<2048, 256, 0, stream>>>(xobuf, vbuf, gbuf, dot, lnx_w, lnx_b, xo_b);
  gemm_wo_kernel<<<dim3(16, 16), 256, 0, stream>>>(xo_b, Wo_b, x, out);
}